// Round 2
// baseline (200.867 us; speedup 1.0000x reference)
//
#include <hip/hip_runtime.h>
#include <math.h>

#define Bv 32
#define Cv 256
#define Hv 32
#define Wv 32
#define Pv 1024   // H*W
#define Tv 4
#define TSTRIDE (Bv * Cv * Pv)   // elements between T-slabs = 8388608

// ---------------------------------------------------------------------------
// Kernel 1: per (b, channel-chunk) partial reduction over channels.
// grid = (nch, B), block = 256; thread t owns pixels [4t, 4t+4) via float4.
// part1[ch][b][p] = sum_c xm, part2[ch][b][p] = sum_c xm^2, xm = mean_T x.
// nch=32 -> 1024 blocks = 4 blocks/CU, 16 waves/CU for BW saturation.
// ---------------------------------------------------------------------------
__global__ __launch_bounds__(256) void lss_partial(
    const float* __restrict__ x,
    float* __restrict__ part1,
    float* __restrict__ part2,
    int cc)   // channels per chunk
{
    const int chunk = blockIdx.x;
    const int b     = blockIdx.y;
    const int tid   = threadIdx.x;
    const int p4    = tid << 2;
    const int c0    = chunk * cc;

    float s1x = 0.f, s1y = 0.f, s1z = 0.f, s1w = 0.f;
    float s2x = 0.f, s2y = 0.f, s2z = 0.f, s2w = 0.f;

    const float* bp = x + ((size_t)b * Cv + c0) * Pv + p4;

    #pragma unroll 4
    for (int c = 0; c < cc; ++c) {
        const float4 v0 = *(const float4*)(bp);
        const float4 v1 = *(const float4*)(bp + (size_t)TSTRIDE);
        const float4 v2 = *(const float4*)(bp + (size_t)2 * TSTRIDE);
        const float4 v3 = *(const float4*)(bp + (size_t)3 * TSTRIDE);
        bp += Pv;

        const float mx = (v0.x + v1.x + v2.x + v3.x) * 0.25f;
        const float my = (v0.y + v1.y + v2.y + v3.y) * 0.25f;
        const float mz = (v0.z + v1.z + v2.z + v3.z) * 0.25f;
        const float mw = (v0.w + v1.w + v2.w + v3.w) * 0.25f;

        s1x += mx;  s2x += mx * mx;
        s1y += my;  s2y += my * my;
        s1z += mz;  s2z += mz * mz;
        s1w += mw;  s2w += mw * mw;
    }

    const size_t o = ((size_t)chunk * Bv + b) * Pv + p4;
    float4 r1; r1.x = s1x; r1.y = s1y; r1.z = s1z; r1.w = s1w;
    float4 r2; r2.x = s2x; r2.y = s2y; r2.z = s2z; r2.w = s2w;
    *(float4*)(part1 + o) = r1;
    *(float4*)(part2 + o) = r2;
}

// ---------------------------------------------------------------------------
// Kernel 2 (mid): reduce the nch chunk-partials -> csum[b][p], nx[b][p].
// grid = (8, B) = 256 blocks (spread across all CUs), 128 threads = 1 pixel ea.
// ---------------------------------------------------------------------------
__global__ __launch_bounds__(128) void lss_mid(
    const float* __restrict__ part1,
    const float* __restrict__ part2,
    float* __restrict__ csum_o,
    float* __restrict__ nx_o,
    int nch)
{
    const int b = blockIdx.y;
    const int p = blockIdx.x * 128 + threadIdx.x;

    float s1 = 0.f, s2 = 0.f;
    for (int ch = 0; ch < nch; ++ch) {
        const size_t o = ((size_t)ch * Bv + b) * Pv + p;
        s1 += part1[o];
        s2 += part2[o];
    }
    csum_o[b * Pv + p] = s1;
    nx_o[b * Pv + p]   = sqrtf(s2);
}

// ---------------------------------------------------------------------------
// Kernel 3: box sum, cosine sim, mask, softmax. 32 blocks x 1024 threads;
// reads only 256 KB (L2-hot). Softmax via wave shuffles: 4 barriers total.
// ---------------------------------------------------------------------------
__global__ __launch_bounds__(1024) void lss_final(
    const float* __restrict__ csum_i,
    const float* __restrict__ nx_i,
    const int*   __restrict__ mask,
    float*       __restrict__ out)
{
    const int b   = blockIdx.x;
    const int tid = threadIdx.x;           // p in [0, 1024)
    const int yy  = tid >> 5;
    const int xx  = tid & 31;
    const int wid = tid >> 6;              // wave id, 16 waves

    __shared__ float cs[(Hv + 2) * (Wv + 2)];   // zero-haloed csum tile
    __shared__ float wred[16];

    const float csum = csum_i[b * Pv + tid];
    const float nx   = nx_i[b * Pv + tid];

    // Zero halo, place interior.
    for (int i = tid; i < (Hv + 2) * (Wv + 2); i += Pv) cs[i] = 0.f;
    __syncthreads();
    cs[(yy + 1) * (Wv + 2) + (xx + 1)] = csum;
    __syncthreads();

    // 3x3 zero-padded box sum / 9.
    float lm = 0.f;
    #pragma unroll
    for (int dy = 0; dy < 3; ++dy)
        #pragma unroll
        for (int dx = 0; dx < 3; ++dx)
            lm += cs[(yy + dy) * (Wv + 2) + (xx + dx)];
    lm *= (1.0f / 9.0f);

    // cosine sim: dot = lm*csum ; ny = sqrt(256)*|lm| = 16*|lm|
    const float ny  = 16.0f * fabsf(lm);
    const float sim = (lm * csum) / (fmaxf(nx, 1e-6f) * fmaxf(ny, 1e-6f));

    const float score = mask[b * Pv + tid] ? -INFINITY : -sim;

    // --- max reduce: wave shuffle (64 lanes) + 16-entry LDS combine ---
    float v = score;
    #pragma unroll
    for (int off = 32; off > 0; off >>= 1)
        v = fmaxf(v, __shfl_xor(v, off, 64));
    if ((tid & 63) == 0) wred[wid] = v;
    __syncthreads();
    float m = wred[0];
    #pragma unroll
    for (int i = 1; i < 16; ++i) m = fmaxf(m, wred[i]);
    __syncthreads();

    const float e = expf(score - m);       // exp(-inf - m) == 0 for masked

    // --- sum reduce ---
    v = e;
    #pragma unroll
    for (int off = 32; off > 0; off >>= 1)
        v += __shfl_xor(v, off, 64);
    if ((tid & 63) == 0) wred[wid] = v;
    __syncthreads();
    float denom = 0.f;
    #pragma unroll
    for (int i = 0; i < 16; ++i) denom += wred[i];

    out[b * Pv + tid] = e / denom;
}

extern "C" void kernel_launch(void* const* d_in, const int* in_sizes, int n_in,
                              void* d_out, int out_size, void* d_ws, size_t ws_size,
                              hipStream_t stream) {
    const float* x    = (const float*)d_in[0];
    const int*   mask = (const int*)d_in[1];
    float*       out  = (float*)d_out;

    // Channel-chunk count sized to workspace: nch*B*P*2 + 2*B*P floats.
    int nch = 32;
    while (nch > 1 &&
           ((size_t)nch * Bv * Pv * 2 + 2 * (size_t)Bv * Pv) * sizeof(float) > ws_size)
        nch >>= 1;
    const int cc = Cv / nch;

    float* part1  = (float*)d_ws;
    float* part2  = part1 + (size_t)nch * Bv * Pv;
    float* csum_b = part2 + (size_t)nch * Bv * Pv;
    float* nx_b   = csum_b + (size_t)Bv * Pv;

    dim3 g1(nch, Bv);
    lss_partial<<<g1, 256, 0, stream>>>(x, part1, part2, cc);
    dim3 g2(Pv / 128, Bv);
    lss_mid<<<g2, 128, 0, stream>>>(part1, part2, csum_b, nx_b, nch);
    lss_final<<<Bv, Pv, 0, stream>>>(csum_b, nx_b, mask, out);
}